// Round 1
// baseline (198.195 us; speedup 1.0000x reference)
//
#include <hip/hip_runtime.h>
#include <math.h>

// Problem constants (match reference)
constexpr int   B_    = 2048;
constexpr int   L_    = 8192;
constexpr int   G_    = 256;
constexpr float BETA_ = 0.01f;

// log(sigmoid(-x)) = -softplus(x) = -(max(x,0) + log1p(exp(-|x|)))  (stable)
__device__ __forceinline__ float log_sigmoid_neg(float x) {
    return -(fmaxf(x, 0.0f) + log1pf(__expf(-fabsf(x))));
}

extern "C" __global__ __launch_bounds__(256)
void meta_loss_kernel(const float* __restrict__ logits,
                      const int*   __restrict__ true_y,
                      const int*   __restrict__ group_ids,
                      float*       __restrict__ out)
{
    __shared__ float s_gl[G_];    // per-group sum of log(1 - sigmoid(logit))
    __shared__ int   s_any[G_];   // per-group "any true label" flag
    __shared__ float s_part[4];   // per-wave partial sums

    const int t = threadIdx.x;
    const int b = blockIdx.x;

    s_gl[t]  = 0.0f;
    s_any[t] = 0;
    __syncthreads();

    const float4* lg = (const float4*)(logits + (size_t)b * L_);
    const int4*   ty = (const int4*)(true_y + (size_t)b * L_);
    const int4*   gi = (const int4*)group_ids;

    // 8192 elems / (4 per thread * 256 threads) = 8 iterations, fully coalesced 16B/lane
    #pragma unroll
    for (int it = 0; it < L_ / (4 * 256); ++it) {
        const int idx = it * 256 + t;
        const float4 x = lg[idx];
        const int4   y = ty[idx];
        const int4   g = gi[idx];

        atomicAdd(&s_gl[g.x], log_sigmoid_neg(x.x));
        atomicAdd(&s_gl[g.y], log_sigmoid_neg(x.y));
        atomicAdd(&s_gl[g.z], log_sigmoid_neg(x.z));
        atomicAdd(&s_gl[g.w], log_sigmoid_neg(x.w));

        // racy identical-value store is safe (everyone writes 1)
        if (y.x) s_any[g.x] = 1;
        if (y.y) s_any[g.y] = 1;
        if (y.z) s_any[g.z] = 1;
        if (y.w) s_any[g.w] = 1;
    }
    __syncthreads();

    // Thread t owns group t (G_ == blockDim.x == 256)
    const float gl = s_gl[t];
    float term;
    if (s_any[t]) {
        term = fmaxf(gl, -100.0f);                    // meta_y = 1: log(p)
    } else {
        // log1p(-exp(gl)); gl==0 (empty or all-certain-zero group) gives -inf -> clamp
        term = fmaxf(log1pf(-__expf(gl)), -100.0f);   // meta_y = 0: log(1-p)
    }

    // wave64 butterfly-free down-reduce, then cross-wave via LDS
    #pragma unroll
    for (int off = 32; off > 0; off >>= 1)
        term += __shfl_down(term, off, 64);
    if ((t & 63) == 0) s_part[t >> 6] = term;
    __syncthreads();

    if (t == 0) {
        const float s = s_part[0] + s_part[1] + s_part[2] + s_part[3];
        // bce = -mean(...)  -> contribution scaled by -BETA / (B*G)
        atomicAdd(out, s * (-BETA_ / ((float)B_ * (float)G_)));
    }
}

extern "C" void kernel_launch(void* const* d_in, const int* in_sizes, int n_in,
                              void* d_out, int out_size, void* d_ws, size_t ws_size,
                              hipStream_t stream) {
    const float* logits    = (const float*)d_in[0];
    const int*   true_y    = (const int*)d_in[1];
    const int*   group_ids = (const int*)d_in[2];
    float*       out       = (float*)d_out;

    // d_out is poisoned 0xAA before every launch; zero it (async memset is capture-safe)
    hipMemsetAsync(out, 0, sizeof(float), stream);

    meta_loss_kernel<<<B_, 256, 0, stream>>>(logits, true_y, group_ids, out);
}

// Round 2
// 197.392 us; speedup vs baseline: 1.0041x; 1.0041x over previous
//
#include <hip/hip_runtime.h>
#include <math.h>

// Problem constants (match reference)
constexpr int   B_    = 2048;
constexpr int   L_    = 8192;
constexpr int   G_    = 256;
constexpr float BETA_ = 0.01f;

// log(sigmoid(-x)) = -softplus(x) = -(max(x,0) + log(1 + exp(-|x|)))
// Fast-intrinsic version: v_exp_f32 + v_log_f32 (~8 VALU instrs total) instead
// of ocml log1pf (~60 instrs). Rel. error ~1e-5, far under the 5e-3 threshold.
__device__ __forceinline__ float log_sigmoid_neg(float x) {
    return -(fmaxf(x, 0.0f) + __logf(1.0f + __expf(-fabsf(x))));
}

extern "C" __global__ __launch_bounds__(256)
void meta_loss_kernel(const float* __restrict__ logits,
                      const int*   __restrict__ true_y,
                      const int*   __restrict__ group_ids,
                      float*       __restrict__ out)
{
    __shared__ float s_gl[G_];    // per-group sum of log(1 - sigmoid(logit))
    __shared__ int   s_any[G_];   // per-group "any true label" flag
    __shared__ float s_part[4];   // per-wave partial sums

    const int t = threadIdx.x;
    const int b = blockIdx.x;

    s_gl[t]  = 0.0f;
    s_any[t] = 0;
    __syncthreads();

    const float4* lg = (const float4*)(logits + (size_t)b * L_);
    const int4*   ty = (const int4*)(true_y + (size_t)b * L_);
    const int4*   gi = (const int4*)group_ids;

    // 8192 elems / (4 per thread * 256 threads) = 8 iterations, fully coalesced 16B/lane
    #pragma unroll
    for (int it = 0; it < L_ / (4 * 256); ++it) {
        const int idx = it * 256 + t;
        const float4 x = lg[idx];
        const int4   y = ty[idx];
        const int4   g = gi[idx];

        atomicAdd(&s_gl[g.x], log_sigmoid_neg(x.x));
        atomicAdd(&s_gl[g.y], log_sigmoid_neg(x.y));
        atomicAdd(&s_gl[g.z], log_sigmoid_neg(x.z));
        atomicAdd(&s_gl[g.w], log_sigmoid_neg(x.w));

        // racy identical-value store is safe (everyone writes 1)
        if (y.x) s_any[g.x] = 1;
        if (y.y) s_any[g.y] = 1;
        if (y.z) s_any[g.z] = 1;
        if (y.w) s_any[g.w] = 1;
    }
    __syncthreads();

    // Thread t owns group t (G_ == blockDim.x == 256)
    const float gl = s_gl[t];
    float term;
    if (s_any[t]) {
        term = fmaxf(gl, -100.0f);                    // meta_y = 1: log(p)
    } else {
        // log1p(-exp(gl)); gl==0 (empty group) gives -inf -> clamp. Rare path,
        // keep libm log1pf for accuracy (1 call/thread, negligible).
        term = fmaxf(log1pf(-__expf(gl)), -100.0f);   // meta_y = 0: log(1-p)
    }

    // wave64 down-reduce, then cross-wave via LDS
    #pragma unroll
    for (int off = 32; off > 0; off >>= 1)
        term += __shfl_down(term, off, 64);
    if ((t & 63) == 0) s_part[t >> 6] = term;
    __syncthreads();

    if (t == 0) {
        const float s = s_part[0] + s_part[1] + s_part[2] + s_part[3];
        // bce = -mean(...)  -> contribution scaled by -BETA / (B*G)
        atomicAdd(out, s * (-BETA_ / ((float)B_ * (float)G_)));
    }
}

extern "C" void kernel_launch(void* const* d_in, const int* in_sizes, int n_in,
                              void* d_out, int out_size, void* d_ws, size_t ws_size,
                              hipStream_t stream) {
    const float* logits    = (const float*)d_in[0];
    const int*   true_y    = (const int*)d_in[1];
    const int*   group_ids = (const int*)d_in[2];
    float*       out       = (float*)d_out;

    // d_out is poisoned 0xAA before every launch; zero it (async memset is capture-safe)
    hipMemsetAsync(out, 0, sizeof(float), stream);

    meta_loss_kernel<<<B_, 256, 0, stream>>>(logits, true_y, group_ids, out);
}